// Round 2
// baseline (816.845 us; speedup 1.0000x reference)
//
#include <hip/hip_runtime.h>
#include <cstdint>
#include <cstddef>

// Problem constants (fixed by the reference)
#define H_DIM 1024
#define I_DIM 4096
#define E_NUM 8
#define TOPK  2
#define T_NUM 4096                 // B*S = 2*2048
#define NROWS (T_NUM * TOPK)       // 8192 assignment rows
#define BK    64                   // K-step in f16 elems: 128 B/row, 8x 16B chunks, XOR-swizzled

typedef _Float16 half8 __attribute__((ext_vector_type(8)));
typedef float    f32x4 __attribute__((ext_vector_type(4)));

// Async global->LDS, 16 B per lane. LDS dest: wave-uniform base + lane*16 (HW rule).
// Global side is per-lane -> supports gathered rows AND source-chunk swizzle.
__device__ __forceinline__ void async_copy16(void* lds, const void* g)
{
    __builtin_amdgcn_global_load_lds(
        (__attribute__((address_space(1))) unsigned int*)g,
        (__attribute__((address_space(3))) unsigned int*)lds,
        16 /*bytes*/, 0 /*offset*/, 0 /*aux*/);
}

// LDS swizzle: tile row t, chunk-position p holds global chunk p ^ (t & 7).
// Staging: lane (rl = lane>>3 rows, c = lane&7 chunk-pos) fetches global chunk c ^ rl
//   (valid because every staging instr covers an 8-row-aligned group: t&7 == rl).
// Reads: to get row fm's k-chunk kc, read chunk-pos kc ^ (fm&7).
//   Bank quad = ((kc^(fm&7))*4)%32 -> 8 distinct quads x 2 lanes = 2-way = free (m136).

// ---------------- fused fp32 -> fp16 conversion (x + 3 weight tensors) ----------------
#define NX4 (T_NUM * H_DIM / 4)
#define NW4 (E_NUM * I_DIM * H_DIM / 4)
__global__ void cvt_all(const float* __restrict__ x,  const float* __restrict__ gp,
                        const float* __restrict__ up, const float* __restrict__ dp,
                        _Float16* __restrict__ xh, _Float16* __restrict__ wg,
                        _Float16* __restrict__ wu, _Float16* __restrict__ wd)
{
    int i = blockIdx.x * blockDim.x + threadIdx.x;
    const int total = NX4 + 3 * NW4;
    if (i >= total) return;
    const float* s; _Float16* d; int j;
    if (i < NX4)              { s = x;  d = xh; j = i; }
    else if (i < NX4 + NW4)   { s = gp; d = wg; j = i - NX4; }
    else if (i < NX4 + 2*NW4) { s = up; d = wu; j = i - NX4 - NW4; }
    else                      { s = dp; d = wd; j = i - NX4 - 2*NW4; }
    float4 v = reinterpret_cast<const float4*>(s)[j];
    union { _Float16 h[4]; unsigned long long u; } o;
    o.h[0] = (_Float16)v.x; o.h[1] = (_Float16)v.y;
    o.h[2] = (_Float16)v.z; o.h[3] = (_Float16)v.w;
    reinterpret_cast<unsigned long long*>(d)[j] = o.u;
}

// ---------------- routing: count + prefix + scatter in one block ----------------
__global__ void route_all(const int* __restrict__ ei, const float* __restrict__ ew,
                          int* __restrict__ offs,
                          int* __restrict__ token_of_row, float* __restrict__ weight_of_row)
{
    __shared__ int cnt[E_NUM];
    __shared__ int cur[E_NUM];
    const int t = (int)threadIdx.x;
    if (t < E_NUM) cnt[t] = 0;
    __syncthreads();
    for (int s = t; s < NROWS; s += (int)blockDim.x) atomicAdd(&cnt[ei[s]], 1);
    __syncthreads();
    if (t == 0) {
        int acc = 0;
        for (int e = 0; e < E_NUM; ++e) { offs[e] = acc; cur[e] = acc; acc += cnt[e]; }
        offs[E_NUM] = acc;  // == NROWS
    }
    __syncthreads();
    for (int s = t; s < NROWS; s += (int)blockDim.x) {
        int e = ei[s];
        int r = atomicAdd(&cur[e], 1);
        token_of_row[r]  = s >> 1;   // TOPK = 2
        weight_of_row[r] = ew[s];
    }
}

// ---------------- fused gate+up grouped GEMM + SiLU*mul ----------------
// Tile: 128 rows x 64 cols of I, K = H = 1024, BK = 64. 4 waves (2x2); wave = 64x32 per matrix.
__global__ __launch_bounds__(256) void gateup_gemm(
    const _Float16* __restrict__ xh,      // [T][H]
    const _Float16* __restrict__ Wg,      // [E][I][H]
    const _Float16* __restrict__ Wu,      // [E][I][H]
    const int*      __restrict__ token_of_row,
    const int*      __restrict__ offs,
    _Float16*       __restrict__ inter)   // [NROWS][I]
{
    const int e = blockIdx.z;
    const int seg_start = offs[e], seg_end = offs[e + 1];
    const int m0 = seg_start + (int)blockIdx.y * 128;
    if (m0 >= seg_end) return;
    const int n0 = (int)blockIdx.x * 64;

    __shared__ _Float16 Ash[128 * BK];   // 16 KB
    __shared__ _Float16 Bgs[64 * BK];    // 8 KB
    __shared__ _Float16 Bus[64 * BK];    // 8 KB

    const int tid  = (int)threadIdx.x;
    const int lane = tid & 63, wid = tid >> 6;
    const int wm = wid >> 1, wn = wid & 1;

    const int c  = lane & 7;      // chunk position (16B units) in 128B row
    const int rl = lane >> 3;     // row within an 8-row staging group
    const int gc = c ^ rl;        // swizzled global chunk to fetch

    // A staging: 16 instrs of 8 rows; this wave does q = 4*wid+j, j=0..3
    const _Float16* pA[4];
    _Float16* lA[4];
#pragma unroll
    for (int j = 0; j < 4; ++j) {
        int q = 4 * wid + j;
        int r = m0 + q * 8 + rl;
        if (r > seg_end - 1) r = seg_end - 1;       // clamp; garbage rows never stored
        int tok = token_of_row[r];
        pA[j] = xh + (size_t)tok * H_DIM + gc * 8;
        lA[j] = &Ash[q * 8 * BK];
    }
    // B staging: 8 instrs each; this wave does q = 2*wid+j, j=0..1
    const _Float16* pBg[2]; const _Float16* pBu[2];
    _Float16* lBg[2]; _Float16* lBu[2];
#pragma unroll
    for (int j = 0; j < 2; ++j) {
        int q = 2 * wid + j;
        int t = q * 8 + rl;
        pBg[j] = Wg + ((size_t)e * I_DIM + n0 + t) * H_DIM + gc * 8;
        pBu[j] = Wu + ((size_t)e * I_DIM + n0 + t) * H_DIM + gc * 8;
        lBg[j] = &Bgs[q * 8 * BK];
        lBu[j] = &Bus[q * 8 * BK];
    }

    f32x4 accg[4][2], accu[4][2];
#pragma unroll
    for (int i = 0; i < 4; ++i)
#pragma unroll
        for (int j = 0; j < 2; ++j) {
            accg[i][j] = (f32x4){0.f, 0.f, 0.f, 0.f};
            accu[i][j] = (f32x4){0.f, 0.f, 0.f, 0.f};
        }

    const int fm = lane & 15, kq = lane >> 4;  // kq = 16B chunk within a K=32 span
    const int sw = fm & 7;                      // read-side swizzle key

    for (int kt = 0; kt < H_DIM / BK; ++kt) {
        const int ko = kt * BK;
        __syncthreads();                       // protect LDS from overwrite
#pragma unroll
        for (int j = 0; j < 4; ++j) async_copy16(lA[j], pA[j] + ko);
#pragma unroll
        for (int j = 0; j < 2; ++j) {
            async_copy16(lBg[j], pBg[j] + ko);
            async_copy16(lBu[j], pBu[j] + ko);
        }
        __syncthreads();                       // vmcnt(0) drain + visibility

#pragma unroll
        for (int h = 0; h < 2; ++h) {          // two K=32 halves of BK=64
            const int kc = h * 4 + kq;         // chunk index within the 8-chunk row
            half8 a[4], bg[2], bu[2];
#pragma unroll
            for (int i = 0; i < 4; ++i)
                a[i] = *(const half8*)&Ash[(wm * 64 + i * 16 + fm) * BK + (kc ^ sw) * 8];
#pragma unroll
            for (int j = 0; j < 2; ++j) {
                bg[j] = *(const half8*)&Bgs[(wn * 32 + j * 16 + fm) * BK + (kc ^ sw) * 8];
                bu[j] = *(const half8*)&Bus[(wn * 32 + j * 16 + fm) * BK + (kc ^ sw) * 8];
            }
#pragma unroll
            for (int i = 0; i < 4; ++i)
#pragma unroll
                for (int j = 0; j < 2; ++j) {
                    accg[i][j] = __builtin_amdgcn_mfma_f32_16x16x32_f16(a[i], bg[j], accg[i][j], 0, 0, 0);
                    accu[i][j] = __builtin_amdgcn_mfma_f32_16x16x32_f16(a[i], bu[j], accu[i][j], 0, 0, 0);
                }
        }
    }

    // Epilogue: inter = silu(g) * u, f16 store. C/D: col=lane&15, row=(lane>>4)*4+reg.
#pragma unroll
    for (int i = 0; i < 4; ++i) {
#pragma unroll
        for (int reg = 0; reg < 4; ++reg) {
            int r = m0 + wm * 64 + i * 16 + kq * 4 + reg;
            if (r < seg_end) {
#pragma unroll
                for (int j = 0; j < 2; ++j) {
                    int col = n0 + wn * 32 + j * 16 + fm;
                    float g = accg[i][j][reg];
                    float u = accu[i][j][reg];
                    float sv = (g / (1.f + __expf(-g))) * u;
                    inter[(size_t)r * I_DIM + col] = (_Float16)sv;
                }
            }
        }
    }
}

// ---------------- down grouped GEMM, weighted atomic scatter-add ----------------
// Tile: 128 rows x 128 cols of H, K = I = 4096, BK = 64. Wave = 64x64, acc[4][4].
__global__ __launch_bounds__(256) void down_gemm(
    const _Float16* __restrict__ inter,   // [NROWS][I]
    const _Float16* __restrict__ Wd,      // [E][H][I]
    const int*      __restrict__ token_of_row,
    const float*    __restrict__ weight_of_row,
    const int*      __restrict__ offs,
    float*          __restrict__ out)     // [T][H], pre-zeroed
{
    const int e = blockIdx.z;
    const int seg_start = offs[e], seg_end = offs[e + 1];
    const int m0 = seg_start + (int)blockIdx.y * 128;
    if (m0 >= seg_end) return;
    const int n0 = (int)blockIdx.x * 128;

    __shared__ _Float16 Ash[128 * BK];   // 16 KB
    __shared__ _Float16 Bsh[128 * BK];   // 16 KB

    const int tid  = (int)threadIdx.x;
    const int lane = tid & 63, wid = tid >> 6;
    const int wm = wid >> 1, wn = wid & 1;
    const int c  = lane & 7;
    const int rl = lane >> 3;
    const int gc = c ^ rl;

    const _Float16* pA[4]; _Float16* lA[4];
    const _Float16* pB[4]; _Float16* lB[4];
#pragma unroll
    for (int j = 0; j < 4; ++j) {
        int q = 4 * wid + j;
        int t = q * 8 + rl;
        int r = m0 + t;
        if (r > seg_end - 1) r = seg_end - 1;
        pA[j] = inter + (size_t)r * I_DIM + gc * 8;
        lA[j] = &Ash[q * 8 * BK];
        pB[j] = Wd + ((size_t)e * H_DIM + n0 + t) * I_DIM + gc * 8;
        lB[j] = &Bsh[q * 8 * BK];
    }

    f32x4 acc[4][4];
#pragma unroll
    for (int i = 0; i < 4; ++i)
#pragma unroll
        for (int j = 0; j < 4; ++j) acc[i][j] = (f32x4){0.f, 0.f, 0.f, 0.f};

    const int fm = lane & 15, kq = lane >> 4;
    const int sw = fm & 7;

    for (int kt = 0; kt < I_DIM / BK; ++kt) {
        const int ko = kt * BK;
        __syncthreads();
#pragma unroll
        for (int j = 0; j < 4; ++j) {
            async_copy16(lA[j], pA[j] + ko);
            async_copy16(lB[j], pB[j] + ko);
        }
        __syncthreads();

#pragma unroll
        for (int h = 0; h < 2; ++h) {
            const int kc = h * 4 + kq;
            half8 a[4], b[4];
#pragma unroll
            for (int i = 0; i < 4; ++i)
                a[i] = *(const half8*)&Ash[(wm * 64 + i * 16 + fm) * BK + (kc ^ sw) * 8];
#pragma unroll
            for (int j = 0; j < 4; ++j)
                b[j] = *(const half8*)&Bsh[(wn * 64 + j * 16 + fm) * BK + (kc ^ sw) * 8];
#pragma unroll
            for (int i = 0; i < 4; ++i)
#pragma unroll
                for (int j = 0; j < 4; ++j)
                    acc[i][j] = __builtin_amdgcn_mfma_f32_16x16x32_f16(a[i], b[j], acc[i][j], 0, 0, 0);
        }
    }

#pragma unroll
    for (int i = 0; i < 4; ++i) {
#pragma unroll
        for (int reg = 0; reg < 4; ++reg) {
            int r = m0 + wm * 64 + i * 16 + kq * 4 + reg;
            if (r < seg_end) {
                float w = weight_of_row[r];
                int   t = token_of_row[r];
#pragma unroll
                for (int j = 0; j < 4; ++j) {
                    int col = n0 + wn * 64 + j * 16 + fm;
                    atomicAdd(&out[(size_t)t * H_DIM + col], w * acc[i][j][reg]);
                }
            }
        }
    }
}

// ---------------- launch ----------------
extern "C" void kernel_launch(void* const* d_in, const int* in_sizes, int n_in,
                              void* d_out, int out_size, void* d_ws, size_t ws_size,
                              hipStream_t stream)
{
    const float* x  = (const float*)d_in[0];
    const int*   ei = (const int*)  d_in[1];
    const float* ew = (const float*)d_in[2];
    const float* gp = (const float*)d_in[3];
    const float* up = (const float*)d_in[4];
    const float* dp = (const float*)d_in[5];
    float* out = (float*)d_out;

    char* ws = (char*)d_ws;
    size_t o = 0;
    _Float16* xh    = (_Float16*)(ws + o); o += (size_t)T_NUM * H_DIM * 2;           // 8 MB
    _Float16* Wg_h  = (_Float16*)(ws + o); o += (size_t)E_NUM * I_DIM * H_DIM * 2;   // 64 MB
    _Float16* Wu_h  = (_Float16*)(ws + o); o += (size_t)E_NUM * I_DIM * H_DIM * 2;
    _Float16* Wd_h  = (_Float16*)(ws + o); o += (size_t)E_NUM * I_DIM * H_DIM * 2;
    _Float16* inter = (_Float16*)(ws + o); o += (size_t)NROWS * I_DIM * 2;           // 64 MB
    int*   offs          = (int*)  (ws + o);
    int*   token_of_row  = (int*)  (ws + o + 256);
    float* weight_of_row = (float*)(ws + o + 256 + (size_t)NROWS * 4);
    size_t ws_need = o + 256 + (size_t)NROWS * 8;
    if (ws_size < ws_need) return;  // diagnostic: absmax will equal |ref|max (~2.16)

    hipMemsetAsync(d_out, 0, (size_t)out_size * sizeof(float), stream);

    const int nt = 256;
    const int ncvt = NX4 + 3 * NW4;
    cvt_all<<<(ncvt + nt - 1) / nt, nt, 0, stream>>>(x, gp, up, dp, xh, Wg_h, Wu_h, Wd_h);

    route_all<<<1, 1024, 0, stream>>>(ei, ew, offs, token_of_row, weight_of_row);

    gateup_gemm<<<dim3(I_DIM / 64, NROWS / 128, E_NUM), 256, 0, stream>>>(
        xh, Wg_h, Wu_h, token_of_row, offs, inter);
    down_gemm<<<dim3(H_DIM / 128, NROWS / 128, E_NUM), 256, 0, stream>>>(
        inter, Wd_h, token_of_row, weight_of_row, offs, out);
}

// Round 3
// 713.355 us; speedup vs baseline: 1.1451x; 1.1451x over previous
//
#include <hip/hip_runtime.h>
#include <cstdint>
#include <cstddef>

// Problem constants (fixed by the reference)
#define H_DIM 1024
#define I_DIM 4096
#define E_NUM 8
#define TOPK  2
#define T_NUM 4096                 // B*S = 2*2048
#define NROWS (T_NUM * TOPK)       // 8192 assignment rows
#define BK    32                   // K-step in f16 elems: 64 B/row = 4x 16B chunks, XOR-swizzled

typedef _Float16 half8 __attribute__((ext_vector_type(8)));
typedef float    f32x4 __attribute__((ext_vector_type(4)));

// Async global->LDS, 16 B per lane. LDS dest: wave-uniform base + lane*16 (HW rule).
// Global side is per-lane -> supports gathered rows AND source-chunk swizzle.
__device__ __forceinline__ void async_copy16(void* lds, const void* g)
{
    __builtin_amdgcn_global_load_lds(
        (__attribute__((address_space(1))) unsigned int*)g,
        (__attribute__((address_space(3))) unsigned int*)lds,
        16 /*bytes*/, 0 /*offset*/, 0 /*aux*/);
}

// Swizzle (BK=32, 64 B rows): tile row t, chunk-pos p holds global chunk p ^ f(t),
//   f(t) = (t&3) ^ ((t>>2)&3).
// Staging instr covers 16 aligned rows: lane = rl*4 + c -> row rl, pos c; fetch global
//   chunk c ^ f(rl) (f depends only on rl since groups are 16-aligned).
// Fragment read: row fm's K-chunk kq lives at pos kq ^ f(fm). Bank quads: each of the
//   16 lanes lands so every bank-quad has exactly 2 lanes -> 2-way = free (m136).

// ---------------- fused fp32 -> fp16 conversion (x + 3 weight tensors) ----------------
#define NX4 (T_NUM * H_DIM / 4)
#define NW4 (E_NUM * I_DIM * H_DIM / 4)
__global__ void cvt_all(const float* __restrict__ x,  const float* __restrict__ gp,
                        const float* __restrict__ up, const float* __restrict__ dp,
                        _Float16* __restrict__ xh, _Float16* __restrict__ wg,
                        _Float16* __restrict__ wu, _Float16* __restrict__ wd)
{
    int i = blockIdx.x * blockDim.x + threadIdx.x;
    const int total = NX4 + 3 * NW4;
    if (i >= total) return;
    const float* s; _Float16* d; int j;
    if (i < NX4)              { s = x;  d = xh; j = i; }
    else if (i < NX4 + NW4)   { s = gp; d = wg; j = i - NX4; }
    else if (i < NX4 + 2*NW4) { s = up; d = wu; j = i - NX4 - NW4; }
    else                      { s = dp; d = wd; j = i - NX4 - 2*NW4; }
    float4 v = reinterpret_cast<const float4*>(s)[j];
    union { _Float16 h[4]; unsigned long long u; } o;
    o.h[0] = (_Float16)v.x; o.h[1] = (_Float16)v.y;
    o.h[2] = (_Float16)v.z; o.h[3] = (_Float16)v.w;
    reinterpret_cast<unsigned long long*>(d)[j] = o.u;
}

// ---------------- routing: count + prefix + scatter in one block ----------------
__global__ void route_all(const int* __restrict__ ei, const float* __restrict__ ew,
                          int* __restrict__ offs,
                          int* __restrict__ token_of_row, float* __restrict__ weight_of_row)
{
    __shared__ int cnt[E_NUM];
    __shared__ int cur[E_NUM];
    const int t = (int)threadIdx.x;
    if (t < E_NUM) cnt[t] = 0;
    __syncthreads();
    for (int s = t; s < NROWS; s += (int)blockDim.x) atomicAdd(&cnt[ei[s]], 1);
    __syncthreads();
    if (t == 0) {
        int acc = 0;
        for (int e = 0; e < E_NUM; ++e) { offs[e] = acc; cur[e] = acc; acc += cnt[e]; }
        offs[E_NUM] = acc;  // == NROWS
    }
    __syncthreads();
    for (int s = t; s < NROWS; s += (int)blockDim.x) {
        int e = ei[s];
        int r = atomicAdd(&cur[e], 1);
        token_of_row[r]  = s >> 1;   // TOPK = 2
        weight_of_row[r] = ew[s];
    }
}

// ---------------- fused gate+up grouped GEMM + SiLU*mul ----------------
// Tile: 128 rows x 64 cols of I, K = H = 1024, BK = 32. 4 waves (2x2); wave = 64x32 per matrix.
__global__ __launch_bounds__(256) void gateup_gemm(
    const _Float16* __restrict__ xh,      // [T][H]
    const _Float16* __restrict__ Wg,      // [E][I][H]
    const _Float16* __restrict__ Wu,      // [E][I][H]
    const int*      __restrict__ token_of_row,
    const int*      __restrict__ offs,
    _Float16*       __restrict__ inter)   // [NROWS][I]
{
    const int e = blockIdx.z;
    const int seg_start = offs[e], seg_end = offs[e + 1];
    const int m0 = seg_start + (int)blockIdx.y * 128;
    if (m0 >= seg_end) return;
    const int n0 = (int)blockIdx.x * 64;

    __shared__ _Float16 Ash[128 * BK];   // 8 KB
    __shared__ _Float16 Bgs[64 * BK];    // 4 KB
    __shared__ _Float16 Bus[64 * BK];    // 4 KB

    const int tid  = (int)threadIdx.x;
    const int lane = tid & 63, wid = tid >> 6;
    const int wm = wid >> 1, wn = wid & 1;

    const int c   = lane & 3;                 // chunk position (16B) in 64B row
    const int rl  = lane >> 2;                // row within 16-row staging group
    const int frl = (rl & 3) ^ (rl >> 2);     // f(t) for staging
    const int gc  = c ^ frl;                  // swizzled global chunk to fetch

    // A staging: 8 instrs of 16 rows; this wave does q = 2*wid, 2*wid+1
    const _Float16* pA[2];
    _Float16* lA[2];
#pragma unroll
    for (int j = 0; j < 2; ++j) {
        int q = 2 * wid + j;
        int r = m0 + q * 16 + rl;
        if (r > seg_end - 1) r = seg_end - 1;       // clamp; garbage rows never stored
        int tok = token_of_row[r];
        pA[j] = xh + (size_t)tok * H_DIM + gc * 8;
        lA[j] = &Ash[q * 16 * BK];
    }
    // B staging: 4 instrs each (64 rows); this wave does q = wid
    const int brow = wid * 16 + rl;
    const _Float16* pBg = Wg + ((size_t)e * I_DIM + n0 + brow) * H_DIM + gc * 8;
    const _Float16* pBu = Wu + ((size_t)e * I_DIM + n0 + brow) * H_DIM + gc * 8;
    _Float16* lBg = &Bgs[wid * 16 * BK];
    _Float16* lBu = &Bus[wid * 16 * BK];

    f32x4 accg[4][2], accu[4][2];
#pragma unroll
    for (int i = 0; i < 4; ++i)
#pragma unroll
        for (int j = 0; j < 2; ++j) {
            accg[i][j] = (f32x4){0.f, 0.f, 0.f, 0.f};
            accu[i][j] = (f32x4){0.f, 0.f, 0.f, 0.f};
        }

    const int fm = lane & 15, kq = lane >> 4;       // kq = 16B K-chunk index (0..3)
    const int fsw = (fm & 3) ^ ((fm >> 2) & 3);     // f(t) for fragment rows
    const int rdo = (kq ^ fsw) * 8;                 // swizzled element offset within row

    for (int kt = 0; kt < H_DIM / BK; ++kt) {
        const int ko = kt * BK;
        __syncthreads();                       // protect LDS from overwrite
        async_copy16(lA[0], pA[0] + ko);
        async_copy16(lA[1], pA[1] + ko);
        async_copy16(lBg,   pBg   + ko);
        async_copy16(lBu,   pBu   + ko);
        __syncthreads();                       // vmcnt(0) drain + visibility

        half8 a[4], bg[2], bu[2];
#pragma unroll
        for (int i = 0; i < 4; ++i)
            a[i] = *(const half8*)&Ash[(wm * 64 + i * 16 + fm) * BK + rdo];
#pragma unroll
        for (int j = 0; j < 2; ++j) {
            bg[j] = *(const half8*)&Bgs[(wn * 32 + j * 16 + fm) * BK + rdo];
            bu[j] = *(const half8*)&Bus[(wn * 32 + j * 16 + fm) * BK + rdo];
        }
#pragma unroll
        for (int i = 0; i < 4; ++i)
#pragma unroll
            for (int j = 0; j < 2; ++j) {
                accg[i][j] = __builtin_amdgcn_mfma_f32_16x16x32_f16(a[i], bg[j], accg[i][j], 0, 0, 0);
                accu[i][j] = __builtin_amdgcn_mfma_f32_16x16x32_f16(a[i], bu[j], accu[i][j], 0, 0, 0);
            }
    }

    // Epilogue: inter = silu(g) * u, f16 store. C/D: col=lane&15, row=(lane>>4)*4+reg.
#pragma unroll
    for (int i = 0; i < 4; ++i) {
#pragma unroll
        for (int reg = 0; reg < 4; ++reg) {
            int r = m0 + wm * 64 + i * 16 + kq * 4 + reg;
            if (r < seg_end) {
#pragma unroll
                for (int j = 0; j < 2; ++j) {
                    int col = n0 + wn * 32 + j * 16 + fm;
                    float g = accg[i][j][reg];
                    float u = accu[i][j][reg];
                    float sv = (g / (1.f + __expf(-g))) * u;
                    inter[(size_t)r * I_DIM + col] = (_Float16)sv;
                }
            }
        }
    }
}

// ---------------- down grouped GEMM, weighted atomic scatter-add ----------------
// Tile: 128 rows x 128 cols of H, K = I = 4096, BK = 32. Wave = 64x64, acc[4][4].
__global__ __launch_bounds__(256) void down_gemm(
    const _Float16* __restrict__ inter,   // [NROWS][I]
    const _Float16* __restrict__ Wd,      // [E][H][I]
    const int*      __restrict__ token_of_row,
    const float*    __restrict__ weight_of_row,
    const int*      __restrict__ offs,
    float*          __restrict__ out)     // [T][H], pre-zeroed
{
    const int e = blockIdx.z;
    const int seg_start = offs[e], seg_end = offs[e + 1];
    const int m0 = seg_start + (int)blockIdx.y * 128;
    if (m0 >= seg_end) return;
    const int n0 = (int)blockIdx.x * 128;

    __shared__ _Float16 Ash[128 * BK];   // 8 KB
    __shared__ _Float16 Bsh[128 * BK];   // 8 KB

    const int tid  = (int)threadIdx.x;
    const int lane = tid & 63, wid = tid >> 6;
    const int wm = wid >> 1, wn = wid & 1;
    const int c   = lane & 3;
    const int rl  = lane >> 2;
    const int frl = (rl & 3) ^ (rl >> 2);
    const int gc  = c ^ frl;

    const _Float16* pA[2]; _Float16* lA[2];
    const _Float16* pB[2]; _Float16* lB[2];
#pragma unroll
    for (int j = 0; j < 2; ++j) {
        int q = 2 * wid + j;
        int row_in = q * 16 + rl;
        int r = m0 + row_in;
        if (r > seg_end - 1) r = seg_end - 1;
        pA[j] = inter + (size_t)r * I_DIM + gc * 8;
        lA[j] = &Ash[q * 16 * BK];
        int n = n0 + row_in;
        pB[j] = Wd + ((size_t)e * H_DIM + n) * I_DIM + gc * 8;
        lB[j] = &Bsh[q * 16 * BK];
    }

    f32x4 acc[4][4];
#pragma unroll
    for (int i = 0; i < 4; ++i)
#pragma unroll
        for (int j = 0; j < 4; ++j) acc[i][j] = (f32x4){0.f, 0.f, 0.f, 0.f};

    const int fm = lane & 15, kq = lane >> 4;
    const int fsw = (fm & 3) ^ ((fm >> 2) & 3);
    const int rdo = (kq ^ fsw) * 8;

    for (int kt = 0; kt < I_DIM / BK; ++kt) {
        const int ko = kt * BK;
        __syncthreads();
        async_copy16(lA[0], pA[0] + ko);
        async_copy16(lA[1], pA[1] + ko);
        async_copy16(lB[0], pB[0] + ko);
        async_copy16(lB[1], pB[1] + ko);
        __syncthreads();

        half8 a[4], b[4];
#pragma unroll
        for (int i = 0; i < 4; ++i)
            a[i] = *(const half8*)&Ash[(wm * 64 + i * 16 + fm) * BK + rdo];
#pragma unroll
        for (int j = 0; j < 4; ++j)
            b[j] = *(const half8*)&Bsh[(wn * 64 + j * 16 + fm) * BK + rdo];
#pragma unroll
        for (int i = 0; i < 4; ++i)
#pragma unroll
            for (int j = 0; j < 4; ++j)
                acc[i][j] = __builtin_amdgcn_mfma_f32_16x16x32_f16(a[i], b[j], acc[i][j], 0, 0, 0);
    }

#pragma unroll
    for (int i = 0; i < 4; ++i) {
#pragma unroll
        for (int reg = 0; reg < 4; ++reg) {
            int r = m0 + wm * 64 + i * 16 + kq * 4 + reg;
            if (r < seg_end) {
                float w = weight_of_row[r];
                int   t = token_of_row[r];
#pragma unroll
                for (int j = 0; j < 4; ++j) {
                    int col = n0 + wn * 64 + j * 16 + fm;
                    atomicAdd(&out[(size_t)t * H_DIM + col], w * acc[i][j][reg]);
                }
            }
        }
    }
}

// ---------------- launch ----------------
extern "C" void kernel_launch(void* const* d_in, const int* in_sizes, int n_in,
                              void* d_out, int out_size, void* d_ws, size_t ws_size,
                              hipStream_t stream)
{
    const float* x  = (const float*)d_in[0];
    const int*   ei = (const int*)  d_in[1];
    const float* ew = (const float*)d_in[2];
    const float* gp = (const float*)d_in[3];
    const float* up = (const float*)d_in[4];
    const float* dp = (const float*)d_in[5];
    float* out = (float*)d_out;

    char* ws = (char*)d_ws;
    size_t o = 0;
    _Float16* xh    = (_Float16*)(ws + o); o += (size_t)T_NUM * H_DIM * 2;           // 8 MB
    _Float16* Wg_h  = (_Float16*)(ws + o); o += (size_t)E_NUM * I_DIM * H_DIM * 2;   // 64 MB
    _Float16* Wu_h  = (_Float16*)(ws + o); o += (size_t)E_NUM * I_DIM * H_DIM * 2;
    _Float16* Wd_h  = (_Float16*)(ws + o); o += (size_t)E_NUM * I_DIM * H_DIM * 2;
    _Float16* inter = (_Float16*)(ws + o); o += (size_t)NROWS * I_DIM * 2;           // 64 MB
    int*   offs          = (int*)  (ws + o);
    int*   token_of_row  = (int*)  (ws + o + 256);
    float* weight_of_row = (float*)(ws + o + 256 + (size_t)NROWS * 4);
    size_t ws_need = o + 256 + (size_t)NROWS * 8;
    if (ws_size < ws_need) return;  // diagnostic: absmax will equal |ref|max (~2.16)

    hipMemsetAsync(d_out, 0, (size_t)out_size * sizeof(float), stream);

    const int nt = 256;
    const int ncvt = NX4 + 3 * NW4;
    cvt_all<<<(ncvt + nt - 1) / nt, nt, 0, stream>>>(x, gp, up, dp, xh, Wg_h, Wu_h, Wd_h);

    route_all<<<1, 1024, 0, stream>>>(ei, ew, offs, token_of_row, weight_of_row);

    gateup_gemm<<<dim3(I_DIM / 64, NROWS / 128, E_NUM), 256, 0, stream>>>(
        xh, Wg_h, Wu_h, token_of_row, offs, inter);
    down_gemm<<<dim3(H_DIM / 128, NROWS / 128, E_NUM), 256, 0, stream>>>(
        inter, Wd_h, token_of_row, weight_of_row, offs, out);
}